// Round 18
// baseline (13790.176 us; speedup 1.0000x reference)
//
#include <hip/hip_runtime.h>
#include <math.h>

#define B  64
#define T  256
#define S  512
#define IN 512
#define H  512
#define P  256
#define C  512

typedef _Float16 f16x8 __attribute__((ext_vector_type(8)));
typedef float    f32x4 __attribute__((ext_vector_type(4)));
typedef unsigned short u16x8 __attribute__((ext_vector_type(8)));

#define MFMA16(a, b, c) __builtin_amdgcn_mfma_f32_16x16x32_f16(a, b, c, 0, 0, 0)

// ---- ws byte offsets ----
#define O_C0      0           /* 131072 */
#define O_C1      131072      /* 131072 */
#define O_H0F0    262144      /* 131072 */
#define O_H1F0    524288      /* 131072 */
#define O_FEEDF   786432      /* 65536 */
#define O_H1F32   851968      /* 131072 ; zero region = [0, 983040) */
#define O_XF0     983040      /* 131072 */
#define O_Q       1245184     /* 131072 */
#define O_PS      1376256     /* 2048: Ps[512] */
#define O_PSP     1378304     /* 131072: pS[64][512] */
#define O_PEA     1509376     /* 1048576: Pea[512][512] */
#define O_BCAT0   2557952
#define O_BCAT1   2566144
#define O_WPROJT  2574336     /* fp16 [1024][256] = 512 KB */
#define O_W0F     3622912     /* fp16 single-plane [x|h0|feed], 5.24 MB */
#define O_PK1A    8865792     /* 524288: fp32 partial gates k1, buf0 */
#define O_PK1B    9390080     /* 524288 */
#define O_PK2A    9914368     /* 524288: fp32 partial gates k2, buf0 */
#define O_PK2B    10438656    /* 524288 */
#define O_W1F     14108672    /* fp16 single-plane [h0|h1], 4.19 MB */
#define O_WATTF   22497280    /* fp16 single-plane, 0.52 MB */
#define O_CTXH    23545856    /* 33554432 fp16 ctx */
#define O_CNTA    57100288    /* cntq[256] dwords, zeroed each call */
#define O_H0F1N   57169920    /* 131072 */
#define O_H1F1N   57300992    /* 131072 */
#define O_XF1N    57432064    /* 131072 ; end 57563136 */

__device__ __forceinline__ float sigm(float x) { return 1.f / (1.f + __expf(-x)); }

__device__ __forceinline__ void split2(float v, unsigned short& hi, unsigned short& lo)
{
    _Float16 h = (_Float16)v;
    float r = (v - (float)h) * 4096.f;
    _Float16 l2 = (_Float16)r;
    union { _Float16 f; unsigned short u; } a, b2;
    a.f = h; b2.f = l2;
    hi = a.u; lo = b2.u;
}

__device__ __forceinline__ unsigned short f2h(float v)
{
    union { _Float16 f; unsigned short u; } x;
    x.f = (_Float16)v;
    return x.u;
}

__device__ __forceinline__ float h2f(unsigned short u)
{
    union { unsigned short u; _Float16 f; } x;
    x.u = u;
    return (float)x.f;
}

// A-fragment layout (segment-local, fp16x2 hi/lo), validated rounds 3-17.
__device__ __forceinline__ int frag_us(int r, int k)
{
    return ((((k >> 5) * 4 + (r >> 4)) * 64 + ((k >> 3) & 3) * 16 + (r & 15)) * 16) + (k & 7);
}

// GEMM core, single-plane fp16 weights with weight sub-range (R17-validated).
__device__ __forceinline__ void gemm_core(
    const unsigned short* A0, int n0, const unsigned short* A1, int n1,
    const unsigned short* A2, const unsigned short* Wf, int wnks, int wbase,
    int nks, int ct, float* red, int tid)
{
    const int l = tid & 63, kh = tid >> 6;
    f32x4 acch[4] = {};
    f32x4 accl[4] = {};
    const int KQ = nks >> 3;
#pragma unroll 2
    for (int i = 0; i < KQ; ++i) {
        const int ks = kh * KQ + i;
        const unsigned short* ap; int ksl;
        if (ks < n0)           { ap = A0; ksl = ks; }
        else if (ks < n0 + n1) { ap = A1; ksl = ks - n0; }
        else                   { ap = A2; ksl = ks - n0 - n1; }
        const f16x8 b = *(const f16x8*)(Wf + ((long)(ct * wnks + wbase + ks) * 64 + l) * 8);
#pragma unroll
        for (int mt = 0; mt < 4; ++mt) {
            const f16x8* app = (const f16x8*)(ap + (((ksl * 4 + mt) * 64 + l) * 16));
            const f16x8 ah = app[0];
            const f16x8 al = app[1];
            acch[mt] = MFMA16(ah, b, acch[mt]);
            accl[mt] = MFMA16(al, b, accl[mt]);
        }
    }
#pragma unroll
    for (int mt = 0; mt < 4; ++mt) {
        f32x4 v = acch[mt] + accl[mt] * (1.f / 4096.f);
        *(f32x4*)&red[(kh * 64 + l) * 20 + mt * 4] = v;
    }
}

// Store raw gate partials (call with tid < 256).
__device__ __forceinline__ void part_store(const float* red, float* Pp,
                                           int ct, int tid)
{
    const int b = tid & 63, hl = tid >> 6;
#pragma unroll
    for (int g = 0; g < 4; ++g) {
        const int col = hl * 4 + g;
        const int li  = ((b & 15) >> 2) * 16 + col;
        const int ri  = (b >> 4) * 4 + (b & 3);
        float v = 0.f;
#pragma unroll
        for (int k2 = 0; k2 < 8; ++k2) v += red[(k2 * 64 + li) * 20 + ri];
        Pp[(ct * 16 + col) * 64 + b] = v;
    }
}

// LSTM pointwise epilogue: bias + stored partial + fresh K-slice (tid < 256).
__device__ __forceinline__ void lstm_epi_p(const float* red, const float* Pp,
                                           const float* bias, float* cbuf,
                                           unsigned short* hfrag, float* hf32_out,
                                           int ct, int tid)
{
    const int b = tid & 63, hl = tid >> 6;
    float g4[4];
#pragma unroll
    for (int g = 0; g < 4; ++g) {
        const int col = hl * 4 + g;
        const int li  = ((b & 15) >> 2) * 16 + col;
        const int ri  = (b >> 4) * 4 + (b & 3);
        float v = bias[ct * 16 + col] + Pp[(ct * 16 + col) * 64 + b];
#pragma unroll
        for (int k2 = 0; k2 < 8; ++k2) v += red[(k2 * 64 + li) * 20 + ri];
        g4[g] = v;
    }
    const int hg = ct * 4 + hl;
    const float cold = cbuf[b * H + hg];
    const float cn = sigm(g4[1]) * cold + sigm(g4[0]) * tanhf(g4[2]);
    cbuf[b * H + hg] = cn;
    const float hn = sigm(g4[3]) * tanhf(cn);
    unsigned short hi, lo; split2(hn, hi, lo);
    const int fu = frag_us(b, hg);
    hfrag[fu]     = hi;
    hfrag[fu + 8] = lo;
    if (hf32_out) hf32_out[b * H + hg] = hn;
}

// ---------------------------------------------------------------------------
// Prologue: Pk1[0] = W0[x|h0-part] @ [x(0); h0(-1)=0]. 128 blocks.
// ---------------------------------------------------------------------------
__global__ __launch_bounds__(512)
void k1part0_kernel(char* __restrict__ wsb)
{
    __shared__ float lds[10240];
    const int bid = blockIdx.x, tid = threadIdx.x;
    gemm_core((unsigned short*)(wsb + O_XF0), 16,
              (unsigned short*)(wsb + O_H0F0), 16, nullptr,
              (const unsigned short*)(wsb + O_W0F), 40, 0, 32, bid, lds, tid);
    __syncthreads();
    if (tid < 256) part_store(lds, (float*)(wsb + O_PK1A), bid, tid);
}

// ---------------------------------------------------------------------------
// d1: K1FIN — feed K-slice (K=256) + Pk1[cur] + epilogue -> h0(t), c0.
// ---------------------------------------------------------------------------
__global__ __launch_bounds__(512)
void k1fin_kernel(char* __restrict__ wsb, int t)
{
    __shared__ float lds[10240];
    const int bid = blockIdx.x, tid = threadIdx.x;
    const int cur = t & 1, nxt = cur ^ 1;
    unsigned short* h0f[2] = {(unsigned short*)(wsb + O_H0F0), (unsigned short*)(wsb + O_H0F1N)};
    const float* Pk1[2] = {(const float*)(wsb + O_PK1A), (const float*)(wsb + O_PK1B)};

    gemm_core((unsigned short*)(wsb + O_FEEDF), 8, nullptr, 0, nullptr,
              (const unsigned short*)(wsb + O_W0F), 40, 32, 8, bid, lds, tid);
    __syncthreads();
    if (tid < 256)
        lstm_epi_p(lds, Pk1[cur], (const float*)(wsb + O_BCAT0),
                   (float*)(wsb + O_C0), h0f[nxt], nullptr, bid, tid);
}

// ---------------------------------------------------------------------------
// d2: K2FIN — h0(t) K-slice (K=512) + Pk2[cur] + epilogue -> h1(t), h1f32.
// ---------------------------------------------------------------------------
__global__ __launch_bounds__(512)
void k2fin_kernel(char* __restrict__ wsb, int t)
{
    __shared__ float lds[10240];
    const int bid = blockIdx.x, tid = threadIdx.x;
    const int cur = t & 1, nxt = cur ^ 1;
    unsigned short* h0f[2] = {(unsigned short*)(wsb + O_H0F0), (unsigned short*)(wsb + O_H0F1N)};
    unsigned short* h1f[2] = {(unsigned short*)(wsb + O_H1F0), (unsigned short*)(wsb + O_H1F1N)};
    const float* Pk2[2] = {(const float*)(wsb + O_PK2A), (const float*)(wsb + O_PK2B)};

    gemm_core(h0f[nxt], 16, nullptr, 0, nullptr,
              (const unsigned short*)(wsb + O_W1F), 32, 0, 16, bid, lds, tid);
    __syncthreads();
    if (tid < 256)
        lstm_epi_p(lds, Pk2[cur], (const float*)(wsb + O_BCAT1),
                   (float*)(wsb + O_C1), h1f[nxt], (float*)(wsb + O_H1F32), bid, tid);
}

// ---------------------------------------------------------------------------
// d3: Q (bid 0-31, scheduled first) + ATTN (32-543) + K1PART(t+1) (544-671)
// + K2PART(t+1) (672-799). Q -> atomicExch qbuf -> cntq; attn blocks issue
// ctx preloads, gate on cntq, then first-touch plain-read qbuf (R10 idiom).
// ---------------------------------------------------------------------------
__global__ __launch_bounds__(512)
void attnq_parts_kernel(char* __restrict__ wsb, const float* __restrict__ mask, int t)
{
    __shared__ char smem[40960];
    const int bid = blockIdx.x, tid = threadIdx.x;
    const int nxt = (t & 1) ^ 1;
    unsigned* cntq = (unsigned*)(wsb + O_CNTA) + t;
    float* qbuf = (float*)(wsb + O_Q);

    if (bid < 32) {
        // ---- Q: q = h1 @ Watt -> atomicExch qbuf, bump cntq ----
        float* red = (float*)smem;
        unsigned short* h1f[2] = {(unsigned short*)(wsb + O_H1F0), (unsigned short*)(wsb + O_H1F1N)};
        gemm_core(h1f[nxt], 16, nullptr, 0, nullptr,
                  (const unsigned short*)(wsb + O_WATTF), 16, 0, 16, bid, red, tid);
        __syncthreads();
        if (tid < 256) {
            const int b = tid & 63, cl = tid >> 6;
            float vv[4];
#pragma unroll
            for (int c2 = 0; c2 < 4; ++c2) {
                const int col = cl * 4 + c2;
                const int li  = ((b & 15) >> 2) * 16 + col;
                const int ri  = (b >> 4) * 4 + (b & 3);
                float v = 0.f;
#pragma unroll
                for (int k2 = 0; k2 < 8; ++k2) v += red[(k2 * 64 + li) * 20 + ri];
                vv[c2] = v;
            }
            float* qp = qbuf + b * C + bid * 16 + cl * 4;
            union { float f[2]; unsigned long long u; } p0, p1;
            p0.f[0] = vv[0]; p0.f[1] = vv[1];
            p1.f[0] = vv[2]; p1.f[1] = vv[3];
            atomicExch((unsigned long long*)qp, p0.u);
            atomicExch(((unsigned long long*)qp) + 1, p1.u);
        }
        __syncthreads();
        if (tid == 0) atomicAdd(cntq, 1u);
        return;
    }

    if (bid >= 544) {
        if (t + 1 >= T) return;
        float* red = (float*)smem;
        unsigned short* h0f[2] = {(unsigned short*)(wsb + O_H0F0), (unsigned short*)(wsb + O_H0F1N)};
        unsigned short* h1f[2] = {(unsigned short*)(wsb + O_H1F0), (unsigned short*)(wsb + O_H1F1N)};
        unsigned short* xf[2]  = {(unsigned short*)(wsb + O_XF0),  (unsigned short*)(wsb + O_XF1N)};
        if (bid < 672) {
            // K1PART(t+1): W0[x|h0] @ [x(t+1); h0(t)] -> Pk1[nxt]
            float* Pk1[2] = {(float*)(wsb + O_PK1A), (float*)(wsb + O_PK1B)};
            gemm_core(xf[nxt], 16, h0f[nxt], 16, nullptr,
                      (const unsigned short*)(wsb + O_W0F), 40, 0, 32, bid - 544, red, tid);
            __syncthreads();
            if (tid < 256) part_store(red, Pk1[nxt], bid - 544, tid);
        } else {
            // K2PART(t+1): W1[h1] @ h1(t) -> Pk2[nxt]
            float* Pk2[2] = {(float*)(wsb + O_PK2A), (float*)(wsb + O_PK2B)};
            gemm_core(h1f[nxt], 16, nullptr, 0, nullptr,
                      (const unsigned short*)(wsb + O_W1F), 32, 16, 16, bid - 672, red, tid);
            __syncthreads();
            if (tid < 256) part_store(red, Pk2[nxt], bid - 672, tid);
        }
        return;
    }

    // ---- attention slice (b, eighth of S); aidx = bid - 32 ----
    float* qs = (float*)smem;                              // 2048 B
    unsigned short* tile = (unsigned short*)(smem + 2048); // 33280 B
    float* scl = (float*)(smem + 35328);                   // 256 B

    const int aidx = bid - 32;
    const int b = aidx >> 3, ei = aidx & 7;
    const unsigned short* ctxh = (const unsigned short*)(wsb + O_CTXH);
    float* pS  = (float*)(wsb + O_PSP);
    float* Ps  = (float*)(wsb + O_PS);
    float* Pea = (float*)(wsb + O_PEA);

    // issue ctx preloads FIRST: they stream while we wait on the q gate
    const unsigned short* cb16 = ctxh + ((long)b * S + ei * 64) * C;
    u16x8 creg[4];
#pragma unroll
    for (int it = 0; it < 4; ++it)
        creg[it] = *(const u16x8*)(cb16 + (long)(it * 512 + tid) * 8);

    // ---- q gate (R10-validated) ----
    if (tid == 0) {
        while (__hip_atomic_load(cntq, __ATOMIC_RELAXED, __HIP_MEMORY_SCOPE_AGENT) < 32u)
            __builtin_amdgcn_s_sleep(2);
    }
    __syncthreads();
    if (tid < 128) ((float4*)qs)[tid] = ((const float4*)(qbuf + (long)b * C))[tid];
    __syncthreads();

    const int row = tid >> 4;
    const int ch  = tid & 15;
    float qv[32];
#pragma unroll
    for (int j = 0; j < 32; ++j) qv[j] = qs[ch * 32 + j];

    float eacc = 0.f;
#pragma unroll
    for (int tt = 0; tt < 2; ++tt) {
#pragma unroll
        for (int it = 0; it < 4; ++it) {
            const int i = it * 512 + tid;
            const int r = (i >> 6) & 31, c8 = i & 63;
            *(u16x8*)&tile[r * 520 + c8 * 8] = creg[it];
        }
        __syncthreads();
        if (tt == 0) {
#pragma unroll
            for (int it = 0; it < 4; ++it)
                creg[it] = *(const u16x8*)(cb16 + 32 * 512 + (long)(it * 512 + tid) * 8);
        }
        float part = 0.f;
#pragma unroll
        for (int j4 = 0; j4 < 4; ++j4) {
            const u16x8 cv = *(const u16x8*)&tile[row * 520 + ch * 32 + j4 * 8];
#pragma unroll
            for (int m = 0; m < 8; ++m)
                part = fmaf(h2f(cv[m]), qv[j4 * 8 + m], part);
        }
        part += __shfl_xor(part, 1);
        part += __shfl_xor(part, 2);
        part += __shfl_xor(part, 4);
        part += __shfl_xor(part, 8);
        if (ch == 0) {
            const int srow = ei * 64 + tt * 32 + row;
            const float sc = part + (mask[(long)b * S + srow] - 1.f) * 1e9f;
            const float p  = __expf(sc - 20.f);
            scl[tt * 32 + row] = p;
            pS[(long)b * S + srow] = p;
        }
        __syncthreads();
#pragma unroll 8
        for (int s = 0; s < 32; ++s)
            eacc = fmaf(scl[tt * 32 + s], h2f(tile[s * 520 + tid]), eacc);
        __syncthreads();
    }

    Pea[(long)aidx * 512 + tid] = eacc;
    if (tid < 64) {
        float v = scl[tid];
#pragma unroll
        for (int off = 32; off; off >>= 1) v += __shfl_xor(v, off);
        if (tid == 0) Ps[aidx] = v;
    }
}

// ---------------------------------------------------------------------------
// d4: MERGEPROJ (blocks 0-63, R14 body) + x-convert(t+2) (blocks 64-127).
// ---------------------------------------------------------------------------
__global__ __launch_bounds__(512)
void mp_kernel(char* __restrict__ wsb, const float* __restrict__ bproj,
               const float* __restrict__ dec_input, float* __restrict__ out, int t)
{
    __shared__ float ectx[512];
    __shared__ float h1l[512];
    __shared__ float red[512];

    const int bid = blockIdx.x, tid = threadIdx.x;
    const int cur = t & 1;

    if (bid >= 64) {
        if (t + 2 < T) {
            unsigned short* xf[2] = {(unsigned short*)(wsb + O_XF0), (unsigned short*)(wsb + O_XF1N)};
            const int idx = (bid - 64) * 512 + tid;     // 0..32767
            const int bb = idx >> 9, k = idx & 511;
            unsigned short hi, lo;
            split2(dec_input[((long)bb * T + (t + 2)) * IN + k], hi, lo);
            unsigned short* dst = xf[cur];              // x(t+2) parity == cur
            const int fu = frag_us(bb, k);
            dst[fu]     = hi;
            dst[fu + 8] = lo;
        }
        return;
    }

    const int b = bid;
    const float* Ps  = (const float*)(wsb + O_PS);
    const float* Pea = (const float*)(wsb + O_PEA);
    const float* pS  = (const float*)(wsb + O_PSP);
    const float* h1f32 = (const float*)(wsb + O_H1F32);
    const unsigned short* Wph = (const unsigned short*)(wsb + O_WPROJT);
    unsigned short* feedf = (unsigned short*)(wsb + O_FEEDF);

    float* dec_out = out;
    float* att_out = out + (long)B * T * P;

    float gs = 0.f;
#pragma unroll
    for (int j = 0; j < 8; ++j) gs += Ps[b * 8 + j];
    const float inv = 1.f / gs;

    float v = 0.f;
#pragma unroll
    for (int j = 0; j < 8; ++j) v += Pea[(long)(b * 8 + j) * 512 + tid];
    ectx[tid] = v * inv;
    h1l[tid]  = h1f32[(long)b * H + tid];
    att_out[((long)b * T + t) * S + tid] = pS[(long)b * S + tid] * inv;
    __syncthreads();

    const int p = tid & 255, half = tid >> 8;
    const float* al = half ? ectx : h1l;
    const unsigned short* Wp = Wph + (long)(half * 512) * P + p;
    float acc = 0.f;
#pragma unroll 8
    for (int kk = 0; kk < 512; ++kk)
        acc = fmaf(al[kk], h2f(Wp[(long)kk * P]), acc);
    red[tid] = acc;
    __syncthreads();

    if (tid < 256) {
        float vv = red[tid] + red[tid + 256] + bproj[tid];
        vv = tanhf(vv);
        dec_out[((long)b * T + t) * P + tid] = vv;
        unsigned short hi, lo; split2(vv, hi, lo);
        const int fu = frag_us(b, tid);
        feedf[fu]     = hi;
        feedf[fu + 8] = lo;
    }
}

// ---------------------------------------------------------------------------
// One-time prep (R17-validated) + cntq zeroing. Grid 8194 x 256.
// ---------------------------------------------------------------------------
__global__ __launch_bounds__(256)
void prep_all(const float* __restrict__ dec_input,
              const float* __restrict__ Wih0, const float* __restrict__ Whh0,
              const float* __restrict__ bih0, const float* __restrict__ bhh0,
              const float* __restrict__ Wih1, const float* __restrict__ Whh1,
              const float* __restrict__ bih1, const float* __restrict__ bhh1,
              const float* __restrict__ Watt, const float* __restrict__ Wproj,
              const float* __restrict__ ctx,
              char* __restrict__ wsb)
{
    const int bid = blockIdx.x, tid = threadIdx.x;
    if (bid < 240) {                                   // zero [0, 983040)
        float4 z = {0.f, 0.f, 0.f, 0.f};
        ((float4*)wsb)[bid * 256 + tid] = z;
    } else if (bid < 368) {                            // x(0) fragments
        const int idx = (bid - 240) * 256 + tid;
        const int bb = idx >> 9, k = idx & 511;
        unsigned short hi, lo;
        split2(dec_input[((long)bb * T) * IN + k], hi, lo);
        unsigned short* xf0 = (unsigned short*)(wsb + O_XF0);
        const int fu = frag_us(bb, k);
        xf0[fu] = hi; xf0[fu + 8] = lo;
    } else if (bid < 384) {                            // combined biases
        const int idx = (bid - 368) * 256 + tid;
        if (idx < 2048) {
            const int p = idx, h = p >> 2, g = p & 3, orig = g * H + h;
            ((float*)(wsb + O_BCAT0))[p] = bih0[orig] + bhh0[orig];
        } else {
            const int p = idx - 2048, h = p >> 2, g = p & 3, orig = g * H + h;
            ((float*)(wsb + O_BCAT1))[p] = bih1[orig] + bhh1[orig];
        }
    } else if (bid < 512) {                            // Wattf single-plane (NKS=16)
        const int idx = (bid - 384) * 256 + tid;
        const int n = idx >> 6, k = (idx & 63) * 8;
        u16x8 hv;
#pragma unroll
        for (int j = 0; j < 8; ++j) hv[j] = f2h(Watt[(long)(k + j) * C + n]);
        unsigned short* Wf = (unsigned short*)(wsb + O_WATTF);
        const long base = ((long)((n >> 4) * 16 + (k >> 5)) * 64 + ((k >> 3) & 3) * 16 + (n & 15)) * 8;
        *(u16x8*)(Wf + base) = hv;
    } else if (bid < 1536) {                           // Wproj fp16 [1024][256]
        const int idx = (bid - 512) * 256 + tid;
        const int k = idx >> 8, p = idx & 255;
        ((unsigned short*)(wsb + O_WPROJT))[k * P + p] = f2h(Wproj[(long)p * (H + C) + k]);
    } else if (bid < 2816) {                           // W0f [x|h0|feed] (NKS=40)
        const int idx = (bid - 1536) * 256 + tid;
        const int n = idx / 160, k8 = idx - n * 160;
        const int k = k8 * 8;
        const int h = n >> 2, g = n & 3, orig = g * H + h;
        const float* src;
        if (k < 512)       src = Wih0 + (long)orig * (IN + P) + k;            // x
        else if (k < 1024) src = Whh0 + (long)orig * H + (k - 512);           // h0
        else               src = Wih0 + (long)orig * (IN + P) + 512 + (k - 1024); // feed
        u16x8 hv;
#pragma unroll
        for (int j = 0; j < 8; ++j) hv[j] = f2h(src[j]);
        unsigned short* Wf = (unsigned short*)(wsb + O_W0F);
        const long base = ((long)((n >> 4) * 40 + (k >> 5)) * 64 + ((k >> 3) & 3) * 16 + (n & 15)) * 8;
        *(u16x8*)(Wf + base) = hv;
    } else if (bid < 3840) {                           // W1f [h0|h1] (NKS=32)
        const int idx = (bid - 2816) * 256 + tid;
        const int n = idx >> 7, k = (idx & 127) * 8;
        const int h = n >> 2, g = n & 3, orig = g * H + h;
        const float* src = (k < H) ? (Wih1 + (long)orig * H + k)
                                   : (Whh1 + (long)orig * H + (k - H));
        u16x8 hv;
#pragma unroll
        for (int j = 0; j < 8; ++j) hv[j] = f2h(src[j]);
        unsigned short* Wf = (unsigned short*)(wsb + O_W1F);
        const long base = ((long)((n >> 4) * 32 + (k >> 5)) * 64 + ((k >> 3) & 3) * 16 + (n & 15)) * 8;
        *(u16x8*)(Wf + base) = hv;
    } else if (bid < 7936) {                           // ctx -> fp16
        const long idx = (long)(bid - 3840) * 256 + tid;
        const float* src = ctx + idx * 16;
        unsigned short* dst = (unsigned short*)(wsb + O_CTXH) + idx * 16;
        u16x8 o0, o1;
#pragma unroll
        for (int j = 0; j < 8; ++j) {
            o0[j] = f2h(src[j]);
            o1[j] = f2h(src[j + 8]);
        }
        *(u16x8*)dst       = o0;
        *(u16x8*)(dst + 8) = o1;
    } else if (bid < 8064) {                           // zero Pk2[0]
        float4 z = {0.f, 0.f, 0.f, 0.f};
        ((float4*)(wsb + O_PK2A))[(bid - 7936) * 256 + tid] = z;
    } else if (bid < 8192) {                           // x(1) fragments -> xf[1]
        const int idx = (bid - 8064) * 256 + tid;      // 0..32767
        const int bb = idx >> 9, k = idx & 511;
        unsigned short hi, lo;
        split2(dec_input[((long)bb * T + 1) * IN + k], hi, lo);
        unsigned short* xf1 = (unsigned short*)(wsb + O_XF1N);
        const int fu = frag_us(bb, k);
        xf1[fu] = hi; xf1[fu + 8] = lo;
    } else if (bid == 8192) {                          // zero cntq[256]
        ((unsigned*)(wsb + O_CNTA))[tid] = 0u;
    }
}

extern "C" void kernel_launch(void* const* d_in, const int* in_sizes, int n_in,
                              void* d_out, int out_size, void* d_ws, size_t ws_size,
                              hipStream_t stream)
{
    (void)in_sizes; (void)n_in; (void)out_size; (void)ws_size;
    const float* dec_input = (const float*)d_in[0];
    const float* ctx       = (const float*)d_in[1];
    const float* mask      = (const float*)d_in[2];
    const float* Wih0      = (const float*)d_in[3];
    const float* Whh0      = (const float*)d_in[4];
    const float* bih0      = (const float*)d_in[5];
    const float* bhh0      = (const float*)d_in[6];
    const float* Wih1      = (const float*)d_in[7];
    const float* Whh1      = (const float*)d_in[8];
    const float* bih1      = (const float*)d_in[9];
    const float* bhh1      = (const float*)d_in[10];
    const float* Watt      = (const float*)d_in[11];
    const float* Wproj     = (const float*)d_in[12];
    const float* bproj     = (const float*)d_in[13];
    float* out = (float*)d_out;
    char*  wsb = (char*)d_ws;

    prep_all<<<8193, 256, 0, stream>>>(dec_input, Wih0, Whh0, bih0, bhh0,
                                       Wih1, Whh1, bih1, bhh1, Watt, Wproj,
                                       ctx, wsb);
    k1part0_kernel<<<128, 512, 0, stream>>>(wsb);

    for (int t = 0; t < T; ++t) {
        k1fin_kernel<<<128, 512, 0, stream>>>(wsb, t);
        k2fin_kernel<<<128, 512, 0, stream>>>(wsb, t);
        attnq_parts_kernel<<<800, 512, 0, stream>>>(wsb, mask, t);
        mp_kernel<<<128, 512, 0, stream>>>(wsb, bproj, dec_input, out, t);
    }
}

// Round 19
// 13050.912 us; speedup vs baseline: 1.0566x; 1.0566x over previous
//
#include <hip/hip_runtime.h>
#include <math.h>

#define B  64
#define T  256
#define S  512
#define IN 512
#define H  512
#define P  256
#define C  512

typedef _Float16 f16x8 __attribute__((ext_vector_type(8)));
typedef float    f32x4 __attribute__((ext_vector_type(4)));
typedef unsigned short u16x8 __attribute__((ext_vector_type(8)));

#define MFMA16(a, b, c) __builtin_amdgcn_mfma_f32_16x16x32_f16(a, b, c, 0, 0, 0)

// ---- ws byte offsets ----
#define O_C0      0           /* 131072 */
#define O_C1      131072      /* 131072 */
#define O_H0F0    262144      /* 131072 */
#define O_H1F0    524288      /* 131072 */
#define O_FEEDF   786432      /* 65536 */
#define O_H1F32   851968      /* 131072 ; zero region = [0, 983040) */
#define O_XF0     983040      /* 131072 */
#define O_Q       1245184     /* 131072 */
#define O_PS      1376256     /* 2048: Ps[512] */
#define O_PSP     1378304     /* 131072: pS[64][512] */
#define O_PEA     1509376     /* 1048576: Pea[512][512] */
#define O_BCAT0   2557952
#define O_BCAT1   2566144
#define O_WPROJT  2574336     /* fp16 [1024][256] = 512 KB */
#define O_W0F     3622912     /* fp16 single-plane [x|h0|feed], 5.24 MB */
#define O_PK1A    8865792     /* 524288: fp32 partial gates k1, buf0 */
#define O_PK1B    9390080     /* 524288 */
#define O_PK2A    9914368     /* 524288: fp32 partial gates k2, buf0 */
#define O_PK2B    10438656    /* 524288 */
#define O_W1F     14108672    /* fp16 single-plane [h0|h1], 4.19 MB */
#define O_WATTF   22497280    /* fp16 single-plane, 0.52 MB */
#define O_CTXH    23545856    /* 33554432 fp16 ctx */
#define O_H0F1N   57169920    /* 131072 */
#define O_H1F1N   57300992    /* 131072 */
#define O_XF1N    57432064    /* 131072 ; end 57563136 */

__device__ __forceinline__ float sigm(float x) { return 1.f / (1.f + __expf(-x)); }

__device__ __forceinline__ void split2(float v, unsigned short& hi, unsigned short& lo)
{
    _Float16 h = (_Float16)v;
    float r = (v - (float)h) * 4096.f;
    _Float16 l2 = (_Float16)r;
    union { _Float16 f; unsigned short u; } a, b2;
    a.f = h; b2.f = l2;
    hi = a.u; lo = b2.u;
}

__device__ __forceinline__ unsigned short f2h(float v)
{
    union { _Float16 f; unsigned short u; } x;
    x.f = (_Float16)v;
    return x.u;
}

__device__ __forceinline__ float h2f(unsigned short u)
{
    union { unsigned short u; _Float16 f; } x;
    x.u = u;
    return (float)x.f;
}

// A-fragment layout (segment-local, fp16x2 hi/lo), validated rounds 3-18.
__device__ __forceinline__ int frag_us(int r, int k)
{
    return ((((k >> 5) * 4 + (r >> 4)) * 64 + ((k >> 3) & 3) * 16 + (r & 15)) * 16) + (k & 7);
}

// GEMM core, single-plane fp16 weights with weight sub-range (R17-validated).
__device__ __forceinline__ void gemm_core(
    const unsigned short* A0, int n0, const unsigned short* A1, int n1,
    const unsigned short* A2, const unsigned short* Wf, int wnks, int wbase,
    int nks, int ct, float* red, int tid)
{
    const int l = tid & 63, kh = tid >> 6;
    f32x4 acch[4] = {};
    f32x4 accl[4] = {};
    const int KQ = nks >> 3;
#pragma unroll 2
    for (int i = 0; i < KQ; ++i) {
        const int ks = kh * KQ + i;
        const unsigned short* ap; int ksl;
        if (ks < n0)           { ap = A0; ksl = ks; }
        else if (ks < n0 + n1) { ap = A1; ksl = ks - n0; }
        else                   { ap = A2; ksl = ks - n0 - n1; }
        const f16x8 b = *(const f16x8*)(Wf + ((long)(ct * wnks + wbase + ks) * 64 + l) * 8);
#pragma unroll
        for (int mt = 0; mt < 4; ++mt) {
            const f16x8* app = (const f16x8*)(ap + (((ksl * 4 + mt) * 64 + l) * 16));
            const f16x8 ah = app[0];
            const f16x8 al = app[1];
            acch[mt] = MFMA16(ah, b, acch[mt]);
            accl[mt] = MFMA16(al, b, accl[mt]);
        }
    }
#pragma unroll
    for (int mt = 0; mt < 4; ++mt) {
        f32x4 v = acch[mt] + accl[mt] * (1.f / 4096.f);
        *(f32x4*)&red[(kh * 64 + l) * 20 + mt * 4] = v;
    }
}

// Store raw gate partials (call with tid < 256).
__device__ __forceinline__ void part_store(const float* red, float* Pp,
                                           int ct, int tid)
{
    const int b = tid & 63, hl = tid >> 6;
#pragma unroll
    for (int g = 0; g < 4; ++g) {
        const int col = hl * 4 + g;
        const int li  = ((b & 15) >> 2) * 16 + col;
        const int ri  = (b >> 4) * 4 + (b & 3);
        float v = 0.f;
#pragma unroll
        for (int k2 = 0; k2 < 8; ++k2) v += red[(k2 * 64 + li) * 20 + ri];
        Pp[(ct * 16 + col) * 64 + b] = v;
    }
}

// LSTM pointwise epilogue: bias + stored partial + fresh K-slice (tid < 256).
__device__ __forceinline__ void lstm_epi_p(const float* red, const float* Pp,
                                           const float* bias, float* cbuf,
                                           unsigned short* hfrag, float* hf32_out,
                                           int ct, int tid)
{
    const int b = tid & 63, hl = tid >> 6;
    float g4[4];
#pragma unroll
    for (int g = 0; g < 4; ++g) {
        const int col = hl * 4 + g;
        const int li  = ((b & 15) >> 2) * 16 + col;
        const int ri  = (b >> 4) * 4 + (b & 3);
        float v = bias[ct * 16 + col] + Pp[(ct * 16 + col) * 64 + b];
#pragma unroll
        for (int k2 = 0; k2 < 8; ++k2) v += red[(k2 * 64 + li) * 20 + ri];
        g4[g] = v;
    }
    const int hg = ct * 4 + hl;
    const float cold = cbuf[b * H + hg];
    const float cn = sigm(g4[1]) * cold + sigm(g4[0]) * tanhf(g4[2]);
    cbuf[b * H + hg] = cn;
    const float hn = sigm(g4[3]) * tanhf(cn);
    unsigned short hi, lo; split2(hn, hi, lo);
    const int fu = frag_us(b, hg);
    hfrag[fu]     = hi;
    hfrag[fu + 8] = lo;
    if (hf32_out) hf32_out[b * H + hg] = hn;
}

// ---------------------------------------------------------------------------
// Prologue: Pk1[0] = W0[x|h0-part] @ [x(0); h0(-1)=0]. 128 blocks.
// ---------------------------------------------------------------------------
__global__ __launch_bounds__(512)
void k1part0_kernel(char* __restrict__ wsb)
{
    __shared__ float lds[10240];
    const int bid = blockIdx.x, tid = threadIdx.x;
    gemm_core((unsigned short*)(wsb + O_XF0), 16,
              (unsigned short*)(wsb + O_H0F0), 16, nullptr,
              (const unsigned short*)(wsb + O_W0F), 40, 0, 32, bid, lds, tid);
    __syncthreads();
    if (tid < 256) part_store(lds, (float*)(wsb + O_PK1A), bid, tid);
}

// ---------------------------------------------------------------------------
// d1: K1FIN — feed K-slice (K=256) + Pk1[cur] + epilogue -> h0(t), c0.
// ---------------------------------------------------------------------------
__global__ __launch_bounds__(512)
void k1fin_kernel(char* __restrict__ wsb, int t)
{
    __shared__ float lds[10240];
    const int bid = blockIdx.x, tid = threadIdx.x;
    const int cur = t & 1, nxt = cur ^ 1;
    unsigned short* h0f[2] = {(unsigned short*)(wsb + O_H0F0), (unsigned short*)(wsb + O_H0F1N)};
    const float* Pk1[2] = {(const float*)(wsb + O_PK1A), (const float*)(wsb + O_PK1B)};

    gemm_core((unsigned short*)(wsb + O_FEEDF), 8, nullptr, 0, nullptr,
              (const unsigned short*)(wsb + O_W0F), 40, 32, 8, bid, lds, tid);
    __syncthreads();
    if (tid < 256)
        lstm_epi_p(lds, Pk1[cur], (const float*)(wsb + O_BCAT0),
                   (float*)(wsb + O_C0), h0f[nxt], nullptr, bid, tid);
}

// ---------------------------------------------------------------------------
// d2: K2FIN — h0(t) K-slice (K=512) + Pk2[cur] + epilogue -> h1(t), h1f32.
// ---------------------------------------------------------------------------
__global__ __launch_bounds__(512)
void k2fin_kernel(char* __restrict__ wsb, int t)
{
    __shared__ float lds[10240];
    const int bid = blockIdx.x, tid = threadIdx.x;
    const int cur = t & 1, nxt = cur ^ 1;
    unsigned short* h0f[2] = {(unsigned short*)(wsb + O_H0F0), (unsigned short*)(wsb + O_H0F1N)};
    unsigned short* h1f[2] = {(unsigned short*)(wsb + O_H1F0), (unsigned short*)(wsb + O_H1F1N)};
    const float* Pk2[2] = {(const float*)(wsb + O_PK2A), (const float*)(wsb + O_PK2B)};

    gemm_core(h0f[nxt], 16, nullptr, 0, nullptr,
              (const unsigned short*)(wsb + O_W1F), 32, 0, 16, bid, lds, tid);
    __syncthreads();
    if (tid < 256)
        lstm_epi_p(lds, Pk2[cur], (const float*)(wsb + O_BCAT1),
                   (float*)(wsb + O_C1), h1f[nxt], (float*)(wsb + O_H1F32), bid, tid);
}

// ---------------------------------------------------------------------------
// d3: Q — q = h1 @ Watt (32 blocks), fp32 out.
// ---------------------------------------------------------------------------
__global__ __launch_bounds__(512)
void q_kernel(char* __restrict__ wsb, int t)
{
    __shared__ float lds[10240];
    const int bid = blockIdx.x, tid = threadIdx.x;
    const int nxt = (t & 1) ^ 1;
    unsigned short* h1f[2] = {(unsigned short*)(wsb + O_H1F0), (unsigned short*)(wsb + O_H1F1N)};
    float* qbuf = (float*)(wsb + O_Q);

    gemm_core(h1f[nxt], 16, nullptr, 0, nullptr,
              (const unsigned short*)(wsb + O_WATTF), 16, 0, 16, bid, lds, tid);
    __syncthreads();
    if (tid < 256) {
        const int b = tid & 63, cl = tid >> 6;
        float4 vv;
#pragma unroll
        for (int c2 = 0; c2 < 4; ++c2) {
            const int col = cl * 4 + c2;
            const int li  = ((b & 15) >> 2) * 16 + col;
            const int ri  = (b >> 4) * 4 + (b & 3);
            float v = 0.f;
#pragma unroll
            for (int k2 = 0; k2 < 8; ++k2) v += lds[(k2 * 64 + li) * 20 + ri];
            ((float*)&vv)[c2] = v;
        }
        *(float4*)(qbuf + b * C + bid * 16 + cl * 4) = vv;
    }
}

// ---------------------------------------------------------------------------
// d4: ATTN (blocks 0-511, R14 body) + K1PART(t+1) (512-639) + K2PART(t+1)
// (640-767). Parts hide under attention's LLC-stream latency.
// ---------------------------------------------------------------------------
__global__ __launch_bounds__(512)
void attn_parts_kernel(char* __restrict__ wsb, const float* __restrict__ mask, int t)
{
    __shared__ char smem[40960];
    const int bid = blockIdx.x, tid = threadIdx.x;
    const int cur = t & 1, nxt = cur ^ 1;

    if (bid >= 512) {
        if (t + 1 >= T) return;
        float* red = (float*)smem;
        unsigned short* h0f[2] = {(unsigned short*)(wsb + O_H0F0), (unsigned short*)(wsb + O_H0F1N)};
        unsigned short* h1f[2] = {(unsigned short*)(wsb + O_H1F0), (unsigned short*)(wsb + O_H1F1N)};
        unsigned short* xf[2]  = {(unsigned short*)(wsb + O_XF0),  (unsigned short*)(wsb + O_XF1N)};
        if (bid < 640) {
            // K1PART(t+1): W0[x|h0] @ [x(t+1); h0(t)] -> Pk1[nxt]
            float* Pk1[2] = {(float*)(wsb + O_PK1A), (float*)(wsb + O_PK1B)};
            gemm_core(xf[nxt], 16, h0f[nxt], 16, nullptr,
                      (const unsigned short*)(wsb + O_W0F), 40, 0, 32, bid - 512, red, tid);
            __syncthreads();
            if (tid < 256) part_store(red, Pk1[nxt], bid - 512, tid);
        } else {
            // K2PART(t+1): W1[h1] @ h1(t) -> Pk2[nxt]
            float* Pk2[2] = {(float*)(wsb + O_PK2A), (float*)(wsb + O_PK2B)};
            gemm_core(h1f[nxt], 16, nullptr, 0, nullptr,
                      (const unsigned short*)(wsb + O_W1F), 32, 16, 16, bid - 640, red, tid);
            __syncthreads();
            if (tid < 256) part_store(red, Pk2[nxt], bid - 640, tid);
        }
        return;
    }

    // ---- attention slice (b, eighth of S) — R14 body, plain stores ----
    float* qs = (float*)smem;                              // 2048 B
    unsigned short* tile = (unsigned short*)(smem + 2048); // 33280 B
    float* scl = (float*)(smem + 35328);                   // 256 B

    const int b = bid >> 3, ei = bid & 7;
    const float* qbuf = (const float*)(wsb + O_Q);
    const unsigned short* ctxh = (const unsigned short*)(wsb + O_CTXH);
    float* pS  = (float*)(wsb + O_PSP);
    float* Ps  = (float*)(wsb + O_PS);
    float* Pea = (float*)(wsb + O_PEA);

    const unsigned short* cb16 = ctxh + ((long)b * S + ei * 64) * C;
    u16x8 creg[4];
#pragma unroll
    for (int it = 0; it < 4; ++it)
        creg[it] = *(const u16x8*)(cb16 + (long)(it * 512 + tid) * 8);

    if (tid < 128) ((float4*)qs)[tid] = ((const float4*)(qbuf + (long)b * C))[tid];
    __syncthreads();

    const int row = tid >> 4;
    const int ch  = tid & 15;
    float qv[32];
#pragma unroll
    for (int j = 0; j < 32; ++j) qv[j] = qs[ch * 32 + j];

    float eacc = 0.f;
#pragma unroll
    for (int tt = 0; tt < 2; ++tt) {
#pragma unroll
        for (int it = 0; it < 4; ++it) {
            const int i = it * 512 + tid;
            const int r = (i >> 6) & 31, c8 = i & 63;
            *(u16x8*)&tile[r * 520 + c8 * 8] = creg[it];
        }
        __syncthreads();
        if (tt == 0) {
#pragma unroll
            for (int it = 0; it < 4; ++it)
                creg[it] = *(const u16x8*)(cb16 + 32 * 512 + (long)(it * 512 + tid) * 8);
        }
        float part = 0.f;
#pragma unroll
        for (int j4 = 0; j4 < 4; ++j4) {
            const u16x8 cv = *(const u16x8*)&tile[row * 520 + ch * 32 + j4 * 8];
#pragma unroll
            for (int m = 0; m < 8; ++m)
                part = fmaf(h2f(cv[m]), qv[j4 * 8 + m], part);
        }
        part += __shfl_xor(part, 1);
        part += __shfl_xor(part, 2);
        part += __shfl_xor(part, 4);
        part += __shfl_xor(part, 8);
        if (ch == 0) {
            const int srow = ei * 64 + tt * 32 + row;
            const float sc = part + (mask[(long)b * S + srow] - 1.f) * 1e9f;
            const float p  = __expf(sc - 20.f);
            scl[tt * 32 + row] = p;
            pS[(long)b * S + srow] = p;
        }
        __syncthreads();
#pragma unroll 8
        for (int s = 0; s < 32; ++s)
            eacc = fmaf(scl[tt * 32 + s], h2f(tile[s * 520 + tid]), eacc);
        __syncthreads();
    }

    Pea[(long)bid * 512 + tid] = eacc;
    if (tid < 64) {
        float v = scl[tid];
#pragma unroll
        for (int off = 32; off; off >>= 1) v += __shfl_xor(v, off);
        if (tid == 0) Ps[bid] = v;
    }
}

// ---------------------------------------------------------------------------
// d5: MERGEPROJ (blocks 0-63, R14 body) + x-convert(t+2) (blocks 64-127).
// ---------------------------------------------------------------------------
__global__ __launch_bounds__(512)
void mp_kernel(char* __restrict__ wsb, const float* __restrict__ bproj,
               const float* __restrict__ dec_input, float* __restrict__ out, int t)
{
    __shared__ float ectx[512];
    __shared__ float h1l[512];
    __shared__ float red[512];

    const int bid = blockIdx.x, tid = threadIdx.x;
    const int cur = t & 1;

    if (bid >= 64) {
        if (t + 2 < T) {
            unsigned short* xf[2] = {(unsigned short*)(wsb + O_XF0), (unsigned short*)(wsb + O_XF1N)};
            const int idx = (bid - 64) * 512 + tid;     // 0..32767
            const int bb = idx >> 9, k = idx & 511;
            unsigned short hi, lo;
            split2(dec_input[((long)bb * T + (t + 2)) * IN + k], hi, lo);
            unsigned short* dst = xf[cur];              // x(t+2) parity == cur
            const int fu = frag_us(bb, k);
            dst[fu]     = hi;
            dst[fu + 8] = lo;
        }
        return;
    }

    const int b = bid;
    const float* Ps  = (const float*)(wsb + O_PS);
    const float* Pea = (const float*)(wsb + O_PEA);
    const float* pS  = (const float*)(wsb + O_PSP);
    const float* h1f32 = (const float*)(wsb + O_H1F32);
    const unsigned short* Wph = (const unsigned short*)(wsb + O_WPROJT);
    unsigned short* feedf = (unsigned short*)(wsb + O_FEEDF);

    float* dec_out = out;
    float* att_out = out + (long)B * T * P;

    float gs = 0.f;
#pragma unroll
    for (int j = 0; j < 8; ++j) gs += Ps[b * 8 + j];
    const float inv = 1.f / gs;

    float v = 0.f;
#pragma unroll
    for (int j = 0; j < 8; ++j) v += Pea[(long)(b * 8 + j) * 512 + tid];
    ectx[tid] = v * inv;
    h1l[tid]  = h1f32[(long)b * H + tid];
    att_out[((long)b * T + t) * S + tid] = pS[(long)b * S + tid] * inv;
    __syncthreads();

    const int p = tid & 255, half = tid >> 8;
    const float* al = half ? ectx : h1l;
    const unsigned short* Wp = Wph + (long)(half * 512) * P + p;
    float acc = 0.f;
#pragma unroll 8
    for (int kk = 0; kk < 512; ++kk)
        acc = fmaf(al[kk], h2f(Wp[(long)kk * P]), acc);
    red[tid] = acc;
    __syncthreads();

    if (tid < 256) {
        float vv = red[tid] + red[tid + 256] + bproj[tid];
        vv = tanhf(vv);
        dec_out[((long)b * T + t) * P + tid] = vv;
        unsigned short hi, lo; split2(vv, hi, lo);
        const int fu = frag_us(b, tid);
        feedf[fu]     = hi;
        feedf[fu + 8] = lo;
    }
}

// ---------------------------------------------------------------------------
// One-time prep: zero state, x0/x1 fragments, biases, single-plane fp16
// weights (W0F reordered [x|h0|feed]), fp16 Wproj, fp16 ctx, zero Pk2[0].
// Grid 8192 x 256.
// ---------------------------------------------------------------------------
__global__ __launch_bounds__(256)
void prep_all(const float* __restrict__ dec_input,
              const float* __restrict__ Wih0, const float* __restrict__ Whh0,
              const float* __restrict__ bih0, const float* __restrict__ bhh0,
              const float* __restrict__ Wih1, const float* __restrict__ Whh1,
              const float* __restrict__ bih1, const float* __restrict__ bhh1,
              const float* __restrict__ Watt, const float* __restrict__ Wproj,
              const float* __restrict__ ctx,
              char* __restrict__ wsb)
{
    const int bid = blockIdx.x, tid = threadIdx.x;
    if (bid < 240) {                                   // zero [0, 983040)
        float4 z = {0.f, 0.f, 0.f, 0.f};
        ((float4*)wsb)[bid * 256 + tid] = z;
    } else if (bid < 368) {                            // x(0) fragments
        const int idx = (bid - 240) * 256 + tid;
        const int bb = idx >> 9, k = idx & 511;
        unsigned short hi, lo;
        split2(dec_input[((long)bb * T) * IN + k], hi, lo);
        unsigned short* xf0 = (unsigned short*)(wsb + O_XF0);
        const int fu = frag_us(bb, k);
        xf0[fu] = hi; xf0[fu + 8] = lo;
    } else if (bid < 384) {                            // combined biases
        const int idx = (bid - 368) * 256 + tid;
        if (idx < 2048) {
            const int p = idx, h = p >> 2, g = p & 3, orig = g * H + h;
            ((float*)(wsb + O_BCAT0))[p] = bih0[orig] + bhh0[orig];
        } else {
            const int p = idx - 2048, h = p >> 2, g = p & 3, orig = g * H + h;
            ((float*)(wsb + O_BCAT1))[p] = bih1[orig] + bhh1[orig];
        }
    } else if (bid < 512) {                            // Wattf single-plane (NKS=16)
        const int idx = (bid - 384) * 256 + tid;
        const int n = idx >> 6, k = (idx & 63) * 8;
        u16x8 hv;
#pragma unroll
        for (int j = 0; j < 8; ++j) hv[j] = f2h(Watt[(long)(k + j) * C + n]);
        unsigned short* Wf = (unsigned short*)(wsb + O_WATTF);
        const long base = ((long)((n >> 4) * 16 + (k >> 5)) * 64 + ((k >> 3) & 3) * 16 + (n & 15)) * 8;
        *(u16x8*)(Wf + base) = hv;
    } else if (bid < 1536) {                           // Wproj fp16 [1024][256]
        const int idx = (bid - 512) * 256 + tid;
        const int k = idx >> 8, p = idx & 255;
        ((unsigned short*)(wsb + O_WPROJT))[k * P + p] = f2h(Wproj[(long)p * (H + C) + k]);
    } else if (bid < 2816) {                           // W0f [x|h0|feed] (NKS=40)
        const int idx = (bid - 1536) * 256 + tid;
        const int n = idx / 160, k8 = idx - n * 160;
        const int k = k8 * 8;
        const int h = n >> 2, g = n & 3, orig = g * H + h;
        const float* src;
        if (k < 512)       src = Wih0 + (long)orig * (IN + P) + k;            // x
        else if (k < 1024) src = Whh0 + (long)orig * H + (k - 512);           // h0
        else               src = Wih0 + (long)orig * (IN + P) + 512 + (k - 1024); // feed
        u16x8 hv;
#pragma unroll
        for (int j = 0; j < 8; ++j) hv[j] = f2h(src[j]);
        unsigned short* Wf = (unsigned short*)(wsb + O_W0F);
        const long base = ((long)((n >> 4) * 40 + (k >> 5)) * 64 + ((k >> 3) & 3) * 16 + (n & 15)) * 8;
        *(u16x8*)(Wf + base) = hv;
    } else if (bid < 3840) {                           // W1f [h0|h1] (NKS=32)
        const int idx = (bid - 2816) * 256 + tid;
        const int n = idx >> 7, k = (idx & 127) * 8;
        const int h = n >> 2, g = n & 3, orig = g * H + h;
        const float* src = (k < H) ? (Wih1 + (long)orig * H + k)
                                   : (Whh1 + (long)orig * H + (k - H));
        u16x8 hv;
#pragma unroll
        for (int j = 0; j < 8; ++j) hv[j] = f2h(src[j]);
        unsigned short* Wf = (unsigned short*)(wsb + O_W1F);
        const long base = ((long)((n >> 4) * 32 + (k >> 5)) * 64 + ((k >> 3) & 3) * 16 + (n & 15)) * 8;
        *(u16x8*)(Wf + base) = hv;
    } else if (bid < 7936) {                           // ctx -> fp16
        const long idx = (long)(bid - 3840) * 256 + tid;
        const float* src = ctx + idx * 16;
        unsigned short* dst = (unsigned short*)(wsb + O_CTXH) + idx * 16;
        u16x8 o0, o1;
#pragma unroll
        for (int j = 0; j < 8; ++j) {
            o0[j] = f2h(src[j]);
            o1[j] = f2h(src[j + 8]);
        }
        *(u16x8*)dst       = o0;
        *(u16x8*)(dst + 8) = o1;
    } else if (bid < 8064) {                           // zero Pk2[0]
        float4 z = {0.f, 0.f, 0.f, 0.f};
        ((float4*)(wsb + O_PK2A))[(bid - 7936) * 256 + tid] = z;
    } else {                                           // x(1) fragments -> xf[1]
        const int idx = (bid - 8064) * 256 + tid;      // 0..32767
        const int bb = idx >> 9, k = idx & 511;
        unsigned short hi, lo;
        split2(dec_input[((long)bb * T + 1) * IN + k], hi, lo);
        unsigned short* xf1 = (unsigned short*)(wsb + O_XF1N);
        const int fu = frag_us(bb, k);
        xf1[fu] = hi; xf1[fu + 8] = lo;
    }
}

extern "C" void kernel_launch(void* const* d_in, const int* in_sizes, int n_in,
                              void* d_out, int out_size, void* d_ws, size_t ws_size,
                              hipStream_t stream)
{
    (void)in_sizes; (void)n_in; (void)out_size; (void)ws_size;
    const float* dec_input = (const float*)d_in[0];
    const float* ctx       = (const float*)d_in[1];
    const float* mask      = (const float*)d_in[2];
    const float* Wih0      = (const float*)d_in[3];
    const float* Whh0      = (const float*)d_in[4];
    const float* bih0      = (const float*)d_in[5];
    const float* bhh0      = (const float*)d_in[6];
    const float* Wih1      = (const float*)d_in[7];
    const float* Whh1      = (const float*)d_in[8];
    const float* bih1      = (const float*)d_in[9];
    const float* bhh1      = (const float*)d_in[10];
    const float* Watt      = (const float*)d_in[11];
    const float* Wproj     = (const float*)d_in[12];
    const float* bproj     = (const float*)d_in[13];
    float* out = (float*)d_out;
    char*  wsb = (char*)d_ws;

    prep_all<<<8192, 256, 0, stream>>>(dec_input, Wih0, Whh0, bih0, bhh0,
                                       Wih1, Whh1, bih1, bhh1, Watt, Wproj,
                                       ctx, wsb);
    k1part0_kernel<<<128, 512, 0, stream>>>(wsb);

    for (int t = 0; t < T; ++t) {
        k1fin_kernel<<<128, 512, 0, stream>>>(wsb, t);
        k2fin_kernel<<<128, 512, 0, stream>>>(wsb, t);
        q_kernel<<<32, 512, 0, stream>>>(wsb, t);
        attn_parts_kernel<<<768, 512, 0, stream>>>(wsb, mask, t);
        mp_kernel<<<128, 512, 0, stream>>>(wsb, bproj, dec_input, out, t);
    }
}